// Round 1
// baseline (248.946 us; speedup 1.0000x reference)
//
#include <hip/hip_runtime.h>
#include <hip/hip_bf16.h>

#define EMBED 768
#define SEQ   2048
#define BATCH 8

typedef __attribute__((ext_vector_type(8))) short bf16x8;
typedef __attribute__((ext_vector_type(4))) float f32x4;
typedef __attribute__((ext_vector_type(8))) unsigned short u16x8;
typedef unsigned short ushort_t;

__device__ inline float bf2f(unsigned short b) {
    unsigned int u = ((unsigned int)b) << 16;
    return __uint_as_float(u);
}
__device__ inline unsigned short f2bf(float f) {
    unsigned int u = __float_as_uint(f);
    unsigned int lsb = (u >> 16) & 1u;
    u += 0x7fffu + lsb;
    return (unsigned short)(u >> 16);
}

// ---------------------------------------------------------------------------
// q = cos(x + theta[e%8]) -> bf16 [b][s][e], and transposed qT bf16 [b][e][s]
// grid (E/64, S/64, B), block 256
// ---------------------------------------------------------------------------
__global__ __launch_bounds__(256)
void build_q(const float* __restrict__ x, const float* __restrict__ theta,
             ushort_t* __restrict__ q, ushort_t* __restrict__ qT)
{
    __shared__ float tile[64][65];
    const int e0 = blockIdx.x * 64;
    const int s0 = blockIdx.y * 64;
    const int b  = blockIdx.z;
    const int le  = threadIdx.x & 63;
    const int grp = threadIdx.x >> 6;
    const float th = theta[le & 7];   // wire index = global e % 8; e0 % 8 == 0

    const float* xb = x + ((size_t)b * SEQ + s0) * EMBED + e0;
    ushort_t*    qb = q + ((size_t)b * SEQ + s0) * EMBED + e0;

    #pragma unroll
    for (int r = 0; r < 16; ++r) {
        const int sl = grp * 16 + r;
        float v = cosf(xb[(size_t)sl * EMBED + le] + th);
        qb[(size_t)sl * EMBED + le] = f2bf(v);
        tile[sl][le] = v;
    }
    __syncthreads();
    ushort_t* qTb = qT + (size_t)b * EMBED * SEQ;
    #pragma unroll
    for (int r = 0; r < 16; ++r) {
        const int el = grp * 16 + r;
        qTb[(size_t)(e0 + el) * SEQ + s0 + le] = f2bf(tile[le][el]);
    }
}

// ---------------------------------------------------------------------------
// W fp32 -> bf16
// ---------------------------------------------------------------------------
__global__ __launch_bounds__(256)
void wconv(const float* __restrict__ W, ushort_t* __restrict__ Wb, int n)
{
    int i = blockIdx.x * 256 + threadIdx.x;
    if (i < n) Wb[i] = f2bf(W[i]);
}

// ---------------------------------------------------------------------------
// gemm_bt: C[M][N] = scale * A[M][K] * B[N][K]^T      (bf16 in, OUT_T out)
// 128x128 tile, BK=32, 256 threads = 4 waves (2x2), each wave 64x64 (4x4 MFMA)
// batched via blockIdx.z strides. All dims must be multiples of 128/32.
// ---------------------------------------------------------------------------
template <typename OUT_T>
__global__ __launch_bounds__(256)
void gemm_bt(const ushort_t* __restrict__ A, const ushort_t* __restrict__ B,
             OUT_T* __restrict__ C,
             int M, int N, int K,
             long long strideA, long long strideB, long long strideC,
             float scale)
{
    __shared__ ushort_t lA[128 * 32];
    __shared__ ushort_t lB[128 * 32];

    const int tid  = threadIdx.x;
    const int lane = tid & 63;
    const int wid  = tid >> 6;
    const int wr   = wid >> 1;        // wave row (0..1)
    const int wc   = wid & 1;         // wave col (0..1)
    const int l16  = lane & 15;
    const int kh   = lane >> 4;       // 0..3

    A += (size_t)blockIdx.z * strideA;
    B += (size_t)blockIdx.z * strideB;
    C += (size_t)blockIdx.z * strideC;

    const int row0 = blockIdx.y * 128;
    const int col0 = blockIdx.x * 128;

    f32x4 acc[4][4];
    #pragma unroll
    for (int m = 0; m < 4; ++m)
        #pragma unroll
        for (int n = 0; n < 4; ++n)
            acc[m][n] = (f32x4)0.f;

    // staging geometry: tile = 8 chunks of 1024B; wave w stages chunks 2w,2w+1
    const int c0   = wid * 2;
    const int srow = lane >> 2;        // row within 16-row chunk
    const int scol = (lane & 3) * 8;   // element offset (16B granules)

    const int nk = K >> 5;
    for (int kk = 0; kk < nk; ++kk) {
        const int k0 = kk << 5;
        __syncthreads();   // previous compute done before overwrite
        #pragma unroll
        for (int c = 0; c < 2; ++c) {
            const int ch = c0 + c;
            const ushort_t* ga = A + (size_t)(row0 + ch * 16 + srow) * K + k0 + scol;
            const ushort_t* gb = B + (size_t)(col0 + ch * 16 + srow) * K + k0 + scol;
            __builtin_amdgcn_global_load_lds(
                (const __attribute__((address_space(1))) void*)ga,
                (__attribute__((address_space(3))) void*)(lA + ch * 512), 16, 0, 0);
            __builtin_amdgcn_global_load_lds(
                (const __attribute__((address_space(1))) void*)gb,
                (__attribute__((address_space(3))) void*)(lB + ch * 512), 16, 0, 0);
        }
        __syncthreads();   // drains vmcnt: staging visible

        bf16x8 af[4], bg[4];
        #pragma unroll
        for (int m = 0; m < 4; ++m)
            af[m] = *(const bf16x8*)&lA[(wr * 64 + m * 16 + l16) * 32 + kh * 8];
        #pragma unroll
        for (int n = 0; n < 4; ++n)
            bg[n] = *(const bf16x8*)&lB[(wc * 64 + n * 16 + l16) * 32 + kh * 8];
        #pragma unroll
        for (int m = 0; m < 4; ++m)
            #pragma unroll
            for (int n = 0; n < 4; ++n)
                acc[m][n] = __builtin_amdgcn_mfma_f32_16x16x32_bf16(af[m], bg[n], acc[m][n], 0, 0, 0);
    }

    // epilogue: C/D layout col = lane&15, row = (lane>>4)*4 + r
    #pragma unroll
    for (int m = 0; m < 4; ++m) {
        #pragma unroll
        for (int n = 0; n < 4; ++n) {
            const int col = col0 + wc * 64 + n * 16 + l16;
            #pragma unroll
            for (int r = 0; r < 4; ++r) {
                const int row = row0 + wr * 64 + m * 16 + kh * 4 + r;
                float v = acc[m][n][r] * scale;
                if constexpr (sizeof(OUT_T) == 2) {
                    ((ushort_t*)C)[(size_t)row * N + col] = f2bf(v);
                } else {
                    ((float*)C)[(size_t)row * N + col] = v;
                }
            }
        }
    }
}

// ---------------------------------------------------------------------------
// in-place row softmax over bf16 rows of length 2048; one block per row,
// whole row held in registers (8 bf16 per thread).
// ---------------------------------------------------------------------------
__global__ __launch_bounds__(256)
void softmax_rows(ushort_t* __restrict__ P)
{
    const size_t row = blockIdx.x;
    ushort_t* p = P + row * 2048;
    const int tid  = threadIdx.x;
    const int lane = tid & 63;
    const int wid  = tid >> 6;

    u16x8 v = *(const u16x8*)&p[tid * 8];
    float f[8];
    float m = -1e30f;
    #pragma unroll
    for (int j = 0; j < 8; ++j) { f[j] = bf2f(v[j]); m = fmaxf(m, f[j]); }
    #pragma unroll
    for (int off = 32; off >= 1; off >>= 1) m = fmaxf(m, __shfl_xor(m, off));

    __shared__ float red[4];
    if (lane == 0) red[wid] = m;
    __syncthreads();
    m = fmaxf(fmaxf(red[0], red[1]), fmaxf(red[2], red[3]));

    float s = 0.f;
    #pragma unroll
    for (int j = 0; j < 8; ++j) { f[j] = __expf(f[j] - m); s += f[j]; }
    #pragma unroll
    for (int off = 32; off >= 1; off >>= 1) s += __shfl_xor(s, off);
    __syncthreads();
    if (lane == 0) red[wid] = s;
    __syncthreads();
    s = red[0] + red[1] + red[2] + red[3];

    const float inv = 1.f / s;
    u16x8 o;
    #pragma unroll
    for (int j = 0; j < 8; ++j) o[j] = f2bf(f[j] * inv);
    *(u16x8*)&p[tid * 8] = o;
}

// ---------------------------------------------------------------------------
extern "C" void kernel_launch(void* const* d_in, const int* in_sizes, int n_in,
                              void* d_out, int out_size, void* d_ws, size_t ws_size,
                              hipStream_t stream)
{
    const float* x     = (const float*)d_in[0];
    const float* theta = (const float*)d_in[1];
    const float* W     = (const float*)d_in[2];
    float* out = (float*)d_out;

    char* ws = (char*)d_ws;
    // layout (bytes):
    //   q    : 8*2048*768*2  = 25165824
    //   qT   : 25165824
    //   Wb   : 768*768*2     = 1179648
    //   P    : 8*2048*2048*2 = 67108864
    // attnout aliases q (q dead after scores GEMM).  total ~113 MB
    ushort_t* q    = (ushort_t*)(ws);
    ushort_t* qT   = (ushort_t*)(ws + 25165824);
    ushort_t* Wb   = (ushort_t*)(ws + 50331648);
    ushort_t* P    = (ushort_t*)(ws + 51511296);
    ushort_t* attn = q;

    dim3 blk(256);

    build_q<<<dim3(EMBED / 64, SEQ / 64, BATCH), blk, 0, stream>>>(x, theta, q, qT);
    wconv<<<dim3((EMBED * EMBED + 255) / 256), blk, 0, stream>>>(W, Wb, EMBED * EMBED);

    // scores = q qT / sqrt(8)  -> P (bf16, pre-softmax)
    gemm_bt<ushort_t><<<dim3(SEQ / 128, SEQ / 128, BATCH), blk, 0, stream>>>(
        q, q, P, SEQ, SEQ, EMBED,
        (long long)SEQ * EMBED, (long long)SEQ * EMBED, (long long)SEQ * SEQ,
        0.35355339059327379f);

    softmax_rows<<<dim3(BATCH * SEQ), blk, 0, stream>>>(P);

    // attnout = P @ q  (B-operand = qT, K = SEQ)
    gemm_bt<ushort_t><<<dim3(EMBED / 128, SEQ / 128, BATCH), blk, 0, stream>>>(
        P, qT, attn, SEQ, EMBED, SEQ,
        (long long)SEQ * SEQ, (long long)EMBED * SEQ, (long long)SEQ * EMBED,
        1.0f);

    // final = attnout @ W^T  (flatten batch: M = 16384)
    gemm_bt<float><<<dim3(EMBED / 128, (BATCH * SEQ) / 128, 1), blk, 0, stream>>>(
        attn, Wb, out, BATCH * SEQ, EMBED, EMBED,
        0, 0, 0, 1.0f);
}

// Round 2
// 173.406 us; speedup vs baseline: 1.4356x; 1.4356x over previous
//
#include <hip/hip_runtime.h>
#include <hip/hip_bf16.h>

#define EMBED 768
#define SEQ   2048
#define BATCH 8

typedef __attribute__((ext_vector_type(8))) short bf16x8;
typedef __attribute__((ext_vector_type(4))) float f32x4;
typedef __attribute__((ext_vector_type(8))) unsigned short u16x8;
typedef unsigned short ushort_t;

__device__ inline float bf2f(unsigned short b) {
    return __uint_as_float(((unsigned int)b) << 16);
}
__device__ inline unsigned short f2bf(float f) {
    unsigned int u = __float_as_uint(f);
    u += 0x7fffu + ((u >> 16) & 1u);
    return (unsigned short)(u >> 16);
}

// ---------------------------------------------------------------------------
// q = cos(x + theta[e%8]) -> bf16 [b][s][e], and transposed qT bf16 [b][e][s]
// ---------------------------------------------------------------------------
__global__ __launch_bounds__(256)
void build_q(const float* __restrict__ x, const float* __restrict__ theta,
             ushort_t* __restrict__ q, ushort_t* __restrict__ qT)
{
    __shared__ float tile[64][65];
    const int e0 = blockIdx.x * 64;
    const int s0 = blockIdx.y * 64;
    const int b  = blockIdx.z;
    const int le  = threadIdx.x & 63;
    const int grp = threadIdx.x >> 6;
    const float th = theta[le & 7];

    const float* xb = x + ((size_t)b * SEQ + s0) * EMBED + e0;
    ushort_t*    qb = q + ((size_t)b * SEQ + s0) * EMBED + e0;

    #pragma unroll
    for (int r = 0; r < 16; ++r) {
        const int sl = grp * 16 + r;
        float v = cosf(xb[(size_t)sl * EMBED + le] + th);
        qb[(size_t)sl * EMBED + le] = f2bf(v);
        tile[sl][le] = v;
    }
    __syncthreads();
    ushort_t* qTb = qT + (size_t)b * EMBED * SEQ;
    #pragma unroll
    for (int r = 0; r < 16; ++r) {
        const int el = grp * 16 + r;
        qTb[(size_t)(e0 + el) * SEQ + s0 + le] = f2bf(tile[le][el]);
    }
}

__global__ __launch_bounds__(256)
void wconv(const float* __restrict__ W, ushort_t* __restrict__ Wb, int n)
{
    int i = blockIdx.x * 256 + threadIdx.x;
    if (i < n) Wb[i] = f2bf(W[i]);
}

// ---------------------------------------------------------------------------
// gemm256_bt: C[M][N] = scale * A[M][K] * B[N][K]^T   (bf16 in, OUT_T out)
// 256x256 tile, BK=64, 512 threads = 8 waves (2Mx4N), per-wave 128x64 out.
// 8-phase schedule (T3+T4), XOR-swizzled LDS (T2) via pre-swizzled global
// source, setprio around MFMA clusters (T5), XCD swizzle (T1).
// LDS: 2 dbuf x (A 256x64 + B 256x64) bf16 = 128 KiB.
// Requires M%256==0, N%256==0, K%128==0, grid count %8==0.
// ---------------------------------------------------------------------------
template <typename OUT_T>
__global__ __launch_bounds__(512)
void gemm256_bt(const ushort_t* __restrict__ A, const ushort_t* __restrict__ B,
                OUT_T* __restrict__ C, int M, int N, int K,
                long long strideA, long long strideB, long long strideC,
                float scale)
{
    __shared__ char lds[131072];

    const int tid  = threadIdx.x;
    const int lane = tid & 63;
    const int wid  = tid >> 6;      // 0..7
    const int wr   = wid >> 2;      // 0..1
    const int wc   = wid & 3;       // 0..3
    const int l16  = lane & 15;
    const int kh   = lane >> 4;     // 0..3

    // XCD-aware swizzle (all our grids have nwg % 8 == 0)
    const int gx  = gridDim.x, gy = gridDim.y;
    const int gxy = gx * gy;
    const int nwg = gxy * gridDim.z;
    int lin = (blockIdx.z * gy + blockIdx.y) * gx + blockIdx.x;
    lin = (lin & 7) * (nwg >> 3) + (lin >> 3);
    const int bz  = lin / gxy;
    const int rm  = lin - bz * gxy;
    const int by  = rm / gx;
    const int bx  = rm - by * gx;

    A += (size_t)bz * strideA;
    B += (size_t)bz * strideB;
    C += (size_t)bz * strideC;
    const int row0 = by * 256;
    const int col0 = bx * 256;

    // ---- staging geometry: per halftile (128 rows x 64 cols), 16 insts of
    // 1024B; wave w issues insts g0,g0+1. Lane covers row g*8+(lane>>3),
    // source col pre-swizzled so linear LDS + XOR-swizzled reads agree.
    const int srow8 = lane >> 3;                    // 0..7
    const int scol  = ((lane & 7) ^ srow8) * 8;     // swizzled elem offset
    const int g0    = wid * 2;

    const ushort_t* gA00 = A + (size_t)(row0 +   0 + (g0+0)*8 + srow8) * K + scol;
    const ushort_t* gA01 = A + (size_t)(row0 +   0 + (g0+1)*8 + srow8) * K + scol;
    const ushort_t* gA10 = A + (size_t)(row0 + 128 + (g0+0)*8 + srow8) * K + scol;
    const ushort_t* gA11 = A + (size_t)(row0 + 128 + (g0+1)*8 + srow8) * K + scol;
    const ushort_t* gB00 = B + (size_t)(col0 +   0 + (g0+0)*8 + srow8) * K + scol;
    const ushort_t* gB01 = B + (size_t)(col0 +   0 + (g0+1)*8 + srow8) * K + scol;
    const ushort_t* gB10 = B + (size_t)(col0 + 128 + (g0+0)*8 + srow8) * K + scol;
    const ushort_t* gB11 = B + (size_t)(col0 + 128 + (g0+1)*8 + srow8) * K + scol;

#define AOFF(b,h) ((b)*65536 + (h)*16384)
#define BOFF(b,h) (32768 + (b)*65536 + (h)*16384)

#define STAGE(p0, p1, region, kt) do {                                         \
    __builtin_amdgcn_global_load_lds(                                          \
        (const __attribute__((address_space(1))) void*)((p0) + (size_t)(kt)*64), \
        (__attribute__((address_space(3))) void*)(lds + (region) + g0*1024),   \
        16, 0, 0);                                                             \
    __builtin_amdgcn_global_load_lds(                                          \
        (const __attribute__((address_space(1))) void*)((p1) + (size_t)(kt)*64), \
        (__attribute__((address_space(3))) void*)(lds + (region) + g0*1024 + 1024), \
        16, 0, 0);                                                             \
} while(0)

    // ---- fragment-read addressing (XOR swizzle (row&7)<<4 on byte offset)
    const int swz  = (l16 & 7) << 4;
    const int cb0  = (kh * 16) ^ swz;          // k-substep 0
    const int cb1  = (64 + kh * 16) ^ swz;     // k-substep 1
    const int arow = wr * 16384 + l16 * 128;
    const int brow = 32768 + (wc >> 1) * 16384 + ((wc & 1) * 64 + l16) * 128;

#define LDSA(b, m, cb) (*(const bf16x8*)(lds + (b)*65536 + arow + (m)*2048 + (cb)))
#define LDSB(b, n, cb) (*(const bf16x8*)(lds + (b)*65536 + brow + (n)*2048 + (cb)))

    f32x4 acc[8][4];
    #pragma unroll
    for (int m = 0; m < 8; ++m)
        #pragma unroll
        for (int n = 0; n < 4; ++n)
            acc[m][n] = (f32x4)0.f;

    bf16x8 bF00, bF01, bF10, bF11, bF20, bF21, bF30, bF31;
    bf16x8 aF00, aF01, aF10, aF11;

#define MFMA_CLUSTER(mp) do {                                                              \
    __builtin_amdgcn_s_setprio(1);                                                         \
    acc[2*(mp)+0][0]=__builtin_amdgcn_mfma_f32_16x16x32_bf16(aF00,bF00,acc[2*(mp)+0][0],0,0,0); \
    acc[2*(mp)+1][0]=__builtin_amdgcn_mfma_f32_16x16x32_bf16(aF10,bF00,acc[2*(mp)+1][0],0,0,0); \
    acc[2*(mp)+0][1]=__builtin_amdgcn_mfma_f32_16x16x32_bf16(aF00,bF10,acc[2*(mp)+0][1],0,0,0); \
    acc[2*(mp)+1][1]=__builtin_amdgcn_mfma_f32_16x16x32_bf16(aF10,bF10,acc[2*(mp)+1][1],0,0,0); \
    acc[2*(mp)+0][2]=__builtin_amdgcn_mfma_f32_16x16x32_bf16(aF00,bF20,acc[2*(mp)+0][2],0,0,0); \
    acc[2*(mp)+1][2]=__builtin_amdgcn_mfma_f32_16x16x32_bf16(aF10,bF20,acc[2*(mp)+1][2],0,0,0); \
    acc[2*(mp)+0][3]=__builtin_amdgcn_mfma_f32_16x16x32_bf16(aF00,bF30,acc[2*(mp)+0][3],0,0,0); \
    acc[2*(mp)+1][3]=__builtin_amdgcn_mfma_f32_16x16x32_bf16(aF10,bF30,acc[2*(mp)+1][3],0,0,0); \
    acc[2*(mp)+0][0]=__builtin_amdgcn_mfma_f32_16x16x32_bf16(aF01,bF01,acc[2*(mp)+0][0],0,0,0); \
    acc[2*(mp)+1][0]=__builtin_amdgcn_mfma_f32_16x16x32_bf16(aF11,bF01,acc[2*(mp)+1][0],0,0,0); \
    acc[2*(mp)+0][1]=__builtin_amdgcn_mfma_f32_16x16x32_bf16(aF01,bF11,acc[2*(mp)+0][1],0,0,0); \
    acc[2*(mp)+1][1]=__builtin_amdgcn_mfma_f32_16x16x32_bf16(aF11,bF11,acc[2*(mp)+1][1],0,0,0); \
    acc[2*(mp)+0][2]=__builtin_amdgcn_mfma_f32_16x16x32_bf16(aF01,bF21,acc[2*(mp)+0][2],0,0,0); \
    acc[2*(mp)+1][2]=__builtin_amdgcn_mfma_f32_16x16x32_bf16(aF11,bF21,acc[2*(mp)+1][2],0,0,0); \
    acc[2*(mp)+0][3]=__builtin_amdgcn_mfma_f32_16x16x32_bf16(aF01,bF31,acc[2*(mp)+0][3],0,0,0); \
    acc[2*(mp)+1][3]=__builtin_amdgcn_mfma_f32_16x16x32_bf16(aF11,bF31,acc[2*(mp)+1][3],0,0,0); \
    __builtin_amdgcn_s_setprio(0);                                                         \
} while(0)

// One phase: ds-read subtile || stage 1 half-tile -> barrier -> lgkmcnt(0)
// -> 16 MFMA -> [counted vmcnt] -> barrier.
#define PHASE(bsel, mp, READS_B, STAGE_STMT, TAIL_WAIT) do {                   \
    if (READS_B) {                                                             \
        bF00 = LDSB(bsel,0,cb0); bF01 = LDSB(bsel,0,cb1);                      \
        bF10 = LDSB(bsel,1,cb0); bF11 = LDSB(bsel,1,cb1);                      \
        bF20 = LDSB(bsel,2,cb0); bF21 = LDSB(bsel,2,cb1);                      \
        bF30 = LDSB(bsel,3,cb0); bF31 = LDSB(bsel,3,cb1);                      \
    }                                                                          \
    aF00 = LDSA(bsel,2*(mp)+0,cb0); aF01 = LDSA(bsel,2*(mp)+0,cb1);            \
    aF10 = LDSA(bsel,2*(mp)+1,cb0); aF11 = LDSA(bsel,2*(mp)+1,cb1);            \
    STAGE_STMT;                                                                \
    if (READS_B) asm volatile("s_waitcnt lgkmcnt(8)");                         \
    __builtin_amdgcn_s_barrier();                                              \
    asm volatile("s_waitcnt lgkmcnt(0)" ::: "memory");                         \
    MFMA_CLUSTER(mp);                                                          \
    TAIL_WAIT;                                                                 \
    __builtin_amdgcn_s_barrier();                                              \
} while(0)

    const int nk    = K >> 6;     // number of 64-wide K-tiles (even)
    const int niter = nk >> 1;

    // Prologue: K-tile 0 -> buf0 (A+B), K-tile 1 B-halves -> buf1.B
    STAGE(gA00, gA01, AOFF(0,0), 0);
    STAGE(gA10, gA11, AOFF(0,1), 0);
    STAGE(gB00, gB01, BOFF(0,0), 0);
    STAGE(gB10, gB11, BOFF(0,1), 0);
    STAGE(gB00, gB01, BOFF(1,0), 1);
    STAGE(gB10, gB11, BOFF(1,1), 1);
    asm volatile("s_waitcnt vmcnt(4)" ::: "memory");   // buf0 landed
    __builtin_amdgcn_s_barrier();

    for (int i = 0; i < niter; ++i) {
        const int kt1 = 2*i + 1;
        const int kt2 = (2*i + 2 < nk) ? (2*i + 2) : (nk - 1);  // clamp: dead
        const int kt3 = (2*i + 3 < nk) ? (2*i + 3) : (nk - 1);  // regions only
        // phases 1-4: compute buf0 (K-tile 2i)
        PHASE(0, 0, true,  STAGE(gA00, gA01, AOFF(1,0), kt1), );
        PHASE(0, 1, false, STAGE(gA10, gA11, AOFF(1,1), kt1), );
        PHASE(0, 2, false, STAGE(gB00, gB01, BOFF(0,0), kt2), );
        PHASE(0, 3, false, STAGE(gB10, gB11, BOFF(0,1), kt2),
              asm volatile("s_waitcnt vmcnt(4)" ::: "memory"));
        // phases 5-8: compute buf1 (K-tile 2i+1)
        PHASE(1, 0, true,  STAGE(gA00, gA01, AOFF(0,0), kt2), );
        PHASE(1, 1, false, STAGE(gA10, gA11, AOFF(0,1), kt2), );
        PHASE(1, 2, false, STAGE(gB00, gB01, BOFF(1,0), kt3), );
        PHASE(1, 3, false, STAGE(gB10, gB11, BOFF(1,1), kt3),
              asm volatile("s_waitcnt vmcnt(4)" ::: "memory"));
    }
    asm volatile("s_waitcnt vmcnt(0)" ::: "memory");   // drain before endpgm

    // Epilogue: C/D layout col = l16, row = kh*4 + r
    const int crow = row0 + wr * 128 + kh * 4;
    const int ccol = col0 + wc * 64 + l16;
    #pragma unroll
    for (int m = 0; m < 8; ++m) {
        #pragma unroll
        for (int n = 0; n < 4; ++n) {
            const int cc = ccol + n * 16;
            #pragma unroll
            for (int r = 0; r < 4; ++r) {
                const int rr = crow + m * 16 + r;
                float v = acc[m][n][r] * scale;
                if constexpr (sizeof(OUT_T) == 2) {
                    ((ushort_t*)C)[(size_t)rr * N + cc] = f2bf(v);
                } else {
                    ((float*)C)[(size_t)rr * N + cc] = v;
                }
            }
        }
    }
#undef AOFF
#undef BOFF
#undef STAGE
#undef LDSA
#undef LDSB
#undef MFMA_CLUSTER
#undef PHASE
}

// ---------------------------------------------------------------------------
// in-place row softmax over bf16 rows of length 2048
// ---------------------------------------------------------------------------
__global__ __launch_bounds__(256)
void softmax_rows(ushort_t* __restrict__ P)
{
    const size_t row = blockIdx.x;
    ushort_t* p = P + row * 2048;
    const int tid  = threadIdx.x;
    const int lane = tid & 63;
    const int wid  = tid >> 6;

    u16x8 v = *(const u16x8*)&p[tid * 8];
    float f[8];
    float m = -1e30f;
    #pragma unroll
    for (int j = 0; j < 8; ++j) { f[j] = bf2f(v[j]); m = fmaxf(m, f[j]); }
    #pragma unroll
    for (int off = 32; off >= 1; off >>= 1) m = fmaxf(m, __shfl_xor(m, off));

    __shared__ float red[4];
    if (lane == 0) red[wid] = m;
    __syncthreads();
    m = fmaxf(fmaxf(red[0], red[1]), fmaxf(red[2], red[3]));

    float s = 0.f;
    #pragma unroll
    for (int j = 0; j < 8; ++j) { f[j] = __expf(f[j] - m); s += f[j]; }
    #pragma unroll
    for (int off = 32; off >= 1; off >>= 1) s += __shfl_xor(s, off);
    __syncthreads();
    if (lane == 0) red[wid] = s;
    __syncthreads();
    s = red[0] + red[1] + red[2] + red[3];

    const float inv = 1.f / s;
    u16x8 o;
    #pragma unroll
    for (int j = 0; j < 8; ++j) o[j] = f2bf(f[j] * inv);
    *(u16x8*)&p[tid * 8] = o;
}

// ---------------------------------------------------------------------------
extern "C" void kernel_launch(void* const* d_in, const int* in_sizes, int n_in,
                              void* d_out, int out_size, void* d_ws, size_t ws_size,
                              hipStream_t stream)
{
    const float* x     = (const float*)d_in[0];
    const float* theta = (const float*)d_in[1];
    const float* W     = (const float*)d_in[2];
    float* out = (float*)d_out;

    char* ws = (char*)d_ws;
    ushort_t* q    = (ushort_t*)(ws);
    ushort_t* qT   = (ushort_t*)(ws + 25165824);
    ushort_t* Wb   = (ushort_t*)(ws + 50331648);
    ushort_t* P    = (ushort_t*)(ws + 51511296);
    ushort_t* attn = q;   // q dead after scores GEMM

    build_q<<<dim3(EMBED / 64, SEQ / 64, BATCH), 256, 0, stream>>>(x, theta, q, qT);
    wconv<<<dim3((EMBED * EMBED + 255) / 256), 256, 0, stream>>>(W, Wb, EMBED * EMBED);

    // scores = q q^T / sqrt(8)  -> P (bf16, pre-softmax)   grid 8x8x8 = 512
    gemm256_bt<ushort_t><<<dim3(SEQ / 256, SEQ / 256, BATCH), 512, 0, stream>>>(
        q, q, P, SEQ, SEQ, EMBED,
        (long long)SEQ * EMBED, (long long)SEQ * EMBED, (long long)SEQ * SEQ,
        0.35355339059327379f);

    softmax_rows<<<dim3(BATCH * SEQ), 256, 0, stream>>>(P);

    // attnout = P @ q  (B = qT, K = SEQ)                   grid 3x8x8 = 192
    gemm256_bt<ushort_t><<<dim3(EMBED / 256, SEQ / 256, BATCH), 512, 0, stream>>>(
        P, qT, attn, SEQ, EMBED, SEQ,
        (long long)SEQ * SEQ, (long long)EMBED * SEQ, (long long)SEQ * EMBED,
        1.0f);

    // final = attnout @ W^T  (flatten batch: M = 16384)    grid 3x64x1 = 192
    gemm256_bt<float><<<dim3(EMBED / 256, (BATCH * SEQ) / 256, 1), 512, 0, stream>>>(
        attn, Wb, out, BATCH * SEQ, EMBED, EMBED,
        0, 0, 0, 1.0f);
}